// Round 7
// baseline (110.495 us; speedup 1.0000x reference)
//
#include <hip/hip_runtime.h>
#include <math.h>

#define N_ 8192
#define P_ 512

typedef __fp16 half8  __attribute__((ext_vector_type(8)));
typedef __fp16 half2t __attribute__((ext_vector_type(2)));
typedef float  floatx16 __attribute__((ext_vector_type(16)));

union H8 { half8 v; half2t h2[4]; };

static __device__ __forceinline__ half2t pk2(float a, float b) {
    return __builtin_amdgcn_cvt_pkrtz(a, b);
}

// Sum across the lane<32 / lane>=32 halves WITHOUT a DS op:
// v_permlane32_swap_b32 with a==b==x swaps the 32-lane halves between the
// two registers; a+b then equals x[i] + x[i^32] in every lane under either
// operand-order convention (symmetric inputs make it interpretation-proof).
static __device__ __forceinline__ float halfsum32(float x) {
    float a = x, b = x;
    asm("v_permlane32_swap_b32 %0, %1" : "+v"(a), "+v"(b));
    return a + b;
}

// LDS region0 (bytes):
//   phase A: bpS 512 rows x 48 halfs (96 B/row) = 49152
//   phase C: g1S (32x264 halfs = 16896) @0 ; hpS (32x33 f32 = 4224) @17408 ;
//            xS (32x25 f32 = 3200) @21760 ; wp2T (16x33 f32 = 2112) @25088
#define HP_OFF   17408
#define XS_OFF   21760
#define WP2T_OFF 25088

// 256 blocks x 512 thr. r4 base (measured 108.55us, best) with:
// 1) p-loop cross-half dot reduce via v_permlane32_swap (VALU) instead of
//    __shfl_xor (DS pipe): removes 512 DS ops + waits from the hot loop.
//    The p-loop is otherwise BYTE-IDENTICAL to r4 (r6 lesson: any added
//    instruction in the issue-bound loop regresses).
// 2) Wp2 register-prefetched post-p-loop, staged transposed+padded
//    (wp2T[16][33]) -> phase-B reads broadcast, no bank conflicts.
// 3) softmax reduce parallelized over 160 threads, 1/S folded into phase B.
__global__ __launch_bounds__(512, 4) void k_fused(
    const float* __restrict__ r,
    const float* __restrict__ rp,
    const float* __restrict__ coeff_x,
    const float* __restrict__ coeff_y,
    const float* __restrict__ Wa1,
    const float* __restrict__ Wa2,
    const float* __restrict__ Wa3,
    const float* __restrict__ Wp1,
    const float* __restrict__ bp1,
    const float* __restrict__ Wp2,
    const float* __restrict__ bp2,
    const float* __restrict__ Wg1,
    const float* __restrict__ bg1,
    const float* __restrict__ Wg2,
    const float* __restrict__ bg2,
    const float* __restrict__ Wg3,
    const float* __restrict__ bg3,
    float* __restrict__ out)
{
    __shared__ __align__(16) unsigned char reg0[49152];
    __shared__ __align__(16) float4 cyS[512];
    __shared__ float sA[8][32];          // also reused as redS
    __shared__ float aoA[4][8][32];
    __shared__ float aoS[32][4];
    __shared__ float sredS[32];

    const int tid  = threadIdx.x;
    const int n0   = blockIdx.x * 32;
    const int lane = tid & 63;
    const int wv   = tid >> 6;           // 8 waves
    const int j32  = lane & 31;
    const int hl   = lane >> 5;
    const int k0g  = hl * 8;

    // ================= Phase A: attention =================
    {
        const float2 cx = ((const float2*)coeff_x)[tid];
        half2t* wrow = (half2t*)(reg0 + tid * 96);
#pragma unroll
        for (int q = 0; q < 16; ++q) {
            const float b0 = cx.x * Wa1[64 + 2*q]     + cx.y * Wa1[96 + 2*q];
            const float b1 = cx.x * Wa1[64 + 2*q + 1] + cx.y * Wa1[96 + 2*q + 1];
            wrow[q] = pk2(b0, b1);
        }
        cyS[tid] = ((const float4*)coeff_y)[tid];
    }

    H8 anh1, anh2;
    {
        const float2 rv = ((const float2*)r)[2 * (n0 + j32)];
#pragma unroll
        for (int q = 0; q < 4; ++q) {
            const int k1 = k0g + 2*q, k2 = 16 + k0g + 2*q;
            anh1.h2[q] = pk2(rv.x*Wa1[k1]   + rv.y*Wa1[32+k1],
                             rv.x*Wa1[k1+1] + rv.y*Wa1[32+k1+1]);
            anh2.h2[q] = pk2(rv.x*Wa1[k2]   + rv.y*Wa1[32+k2],
                             rv.x*Wa1[k2+1] + rv.y*Wa1[32+k2+1]);
        }
    }
    H8 af1, af2;
#pragma unroll
    for (int q = 0; q < 4; ++q) {
        af1.h2[q] = pk2(Wa2[(k0g + 2*q)     * 32 + j32],
                        Wa2[(k0g + 2*q + 1) * 32 + j32]);
        af2.h2[q] = pk2(Wa2[(16 + k0g + 2*q)     * 32 + j32],
                        Wa2[(16 + k0g + 2*q + 1) * 32 + j32]);
    }
    half2t w3h[8];
#pragma unroll
    for (int q = 0; q < 8; ++q) {
        const int r0 = ((2*q) & 3) + 8*(q >> 1) + 4*hl;
        w3h[q] = pk2(Wa3[r0], Wa3[r0 + 1]);
    }

    __syncthreads();

    const half2t zero2 = pk2(0.f, 0.f);
    float s = 0.0f, aox = 0.f, aoy = 0.f, aoz = 0.f, aow = 0.f;

#pragma unroll 2
    for (int pl = 0; pl < 64; ++pl) {
        const int ploc = wv * 64 + pl;
        const half2t* rowq = (const half2t*)(reg0 + ploc * 96) + hl * 4;

        H8 bf1, bf2;
#pragma unroll
        for (int q = 0; q < 4; ++q) {
            bf1.h2[q] = __builtin_elementwise_max(anh1.h2[q] + rowq[q],     zero2);
            bf2.h2[q] = __builtin_elementwise_max(anh2.h2[q] + rowq[8 + q], zero2);
        }

        floatx16 zc = {};
        floatx16 acc = __builtin_amdgcn_mfma_f32_32x32x16_f16(af1.v, bf1.v, zc, 0, 0, 0);
        acc = __builtin_amdgcn_mfma_f32_32x32x16_f16(af2.v, bf2.v, acc, 0, 0, 0);

        float d0, d1, d2, d3;
        {
            half2t z0 = __builtin_elementwise_max(pk2(acc[0],  acc[1]),  zero2);
            half2t z1 = __builtin_elementwise_max(pk2(acc[2],  acc[3]),  zero2);
            half2t z2 = __builtin_elementwise_max(pk2(acc[4],  acc[5]),  zero2);
            half2t z3 = __builtin_elementwise_max(pk2(acc[6],  acc[7]),  zero2);
            half2t z4 = __builtin_elementwise_max(pk2(acc[8],  acc[9]),  zero2);
            half2t z5 = __builtin_elementwise_max(pk2(acc[10], acc[11]), zero2);
            half2t z6 = __builtin_elementwise_max(pk2(acc[12], acc[13]), zero2);
            half2t z7 = __builtin_elementwise_max(pk2(acc[14], acc[15]), zero2);
            d0 = __builtin_amdgcn_fdot2(z1, w3h[1], __builtin_amdgcn_fdot2(z0, w3h[0], 0.f, false), false);
            d1 = __builtin_amdgcn_fdot2(z3, w3h[3], __builtin_amdgcn_fdot2(z2, w3h[2], 0.f, false), false);
            d2 = __builtin_amdgcn_fdot2(z5, w3h[5], __builtin_amdgcn_fdot2(z4, w3h[4], 0.f, false), false);
            d3 = __builtin_amdgcn_fdot2(z7, w3h[7], __builtin_amdgcn_fdot2(z6, w3h[6], 0.f, false), false);
        }
        const float dot = halfsum32((d0 + d1) + (d2 + d3));

        const float e = __expf(dot);   // logits ~N(0,1.3): no-max-sub safe
        const float4 cyv = cyS[ploc];
        s   += e;
        aox += e * cyv.x;
        aoy += e * cyv.y;
        aoz += e * cyv.z;
        aow += e * cyv.w;
    }

    // -------- post-p-loop cold-HBM batched prefetch (phase B/C weights).
    // All loads issue concurrently; one ~900cyc round trip drained by the
    // sA barrier instead of serial per-use stalls. r4-proven sizes. ------
    const int jcol = (wv << 5) + j32;
    const int nB = tid & 31;
    const int iB = tid >> 5;             // 0..15

    float wg2p[32];                      // GEMM2 batch c=0 (rows 0..63)
#pragma unroll
    for (int q = 0; q < 4; ++q)
#pragma unroll
        for (int t = 0; t < 4; ++t) {
            const int kb = q*16 + hl*8 + 2*t;
            wg2p[q*8 + 2*t]     = Wg2[kb*256 + jcol];
            wg2p[q*8 + 2*t + 1] = Wg2[(kb+1)*256 + jcol];
        }
    float wg1f[8], wg1g[8];
    const float bg1v = bg1[jcol];
#pragma unroll
    for (int q = 0; q < 4; ++q) {
        wg1f[2*q]   = Wg1[(k0g + 2*q)*256 + jcol];
        wg1f[2*q+1] = Wg1[(k0g + 2*q + 1)*256 + jcol];
        wg1g[2*q]   = Wg1[(16 + 2*q)*256 + jcol];
        wg1g[2*q+1] = Wg1[(17 + 2*q)*256 + jcol];
    }
    const float wp2pre = Wp2[tid];       // 32x16 = 512 f32, one per thread
    float xpre = 0.f;
    if (tid < 256) {
        const int nn = tid >> 3, k = tid & 7;
        xpre = (k < 4) ? r[(n0+nn)*4 + k] : rp[(n0+nn)*4 + k - 4];
    }
    float wpb[2], wpA[2][4];
#pragma unroll
    for (int rep = 0; rep < 2; ++rep) {
        const int i = iB + rep*16;
        wpb[rep]    = bp1[i];
        wpA[rep][0] = Wp1[i];
        wpA[rep][1] = Wp1[32 + i];
        wpA[rep][2] = Wp1[64 + i];
        wpA[rep][3] = Wp1[96 + i];
    }
    const float bp2v = bp2[iB];
    const float bg2v = bg2[jcol];
    const float w3vv = Wg3[jcol];
    const float bg3v = bg3[0];

    if (lane < 32) {
        sA[wv][lane]      = s;
        aoA[0][wv][lane]  = aox;
        aoA[1][wv][lane]  = aoy;
        aoA[2][wv][lane]  = aoz;
        aoA[3][wv][lane]  = aow;
    }
    __syncthreads();

    // parallel softmax reduce (160 thr; raw sums, 1/S folded into phase B).
    // All threads stage Wp2 transposed+padded: wp2T[col][row], stride 33 ->
    // phase-B reads wp2T[iB][i] are BROADCAST (uniform per 32-lane group).
    float* wp2T = (float*)(reg0 + WP2T_OFF);
    wp2T[(tid & 15) * 33 + (tid >> 4)] = wp2pre;
    if (tid < 160) {
        const int g5 = tid >> 5, c = tid & 31;
        if (g5 == 0) {
            float S = 0.f;
#pragma unroll
            for (int w = 0; w < 8; ++w) S += sA[w][c];
            sredS[c] = S;
        } else {
            float A = 0.f;
#pragma unroll
            for (int w = 0; w < 8; ++w) A += aoA[g5-1][w][c];
            aoS[c][g5-1] = A;
        }
    }
    __syncthreads();

    // ================= Phase B: c-MLP + x assembly =================
    float* hpS = (float*)(reg0 + HP_OFF);
    float* xS  = (float*)(reg0 + XS_OFF);

    if (tid < 256) {
        const int nn = tid >> 3, k = tid & 7;
        xS[nn*25 + k] = xpre;
    }
    {
        const float inv = 1.0f / sredS[nB];
        const float a0 = aoS[nB][0], a1 = aoS[nB][1], a2 = aoS[nB][2], a3 = aoS[nB][3];
#pragma unroll
        for (int rep = 0; rep < 2; ++rep) {
            float t = a0*wpA[rep][0] + a1*wpA[rep][1]
                    + a2*wpA[rep][2] + a3*wpA[rep][3];
            float a = wpb[rep] + inv * t;
            hpS[nB*33 + iB + rep*16] = fmaxf(a, 0.0f);
        }
    }
    __syncthreads();

    {
        float a = bp2v;
#pragma unroll
        for (int i = 0; i < 32; ++i) a += hpS[nB*33 + i] * wp2T[iB*33 + i];
        xS[nB*25 + 8 + iB] = a;
    }
    __syncthreads();

    // ================= Phase C: g-network via MFMA =================
    __fp16* g1S = (__fp16*)reg0;

    // GEMM1: g1 = relu(x @ Wg1 + bg1), K=24 padded to 32
    {
        H8 xa1, xa2, wb1, wb2;
        const float* xrow = xS + j32 * 25;
#pragma unroll
        for (int q = 0; q < 4; ++q) {
            xa1.h2[q] = pk2(xrow[k0g + 2*q], xrow[k0g + 2*q + 1]);
            wb1.h2[q] = pk2(wg1f[2*q], wg1f[2*q+1]);
            if (hl == 0) {
                xa2.h2[q] = pk2(xrow[16 + 2*q], xrow[16 + 2*q + 1]);
                wb2.h2[q] = pk2(wg1g[2*q], wg1g[2*q+1]);
            } else {
                xa2.h2[q] = pk2(0.f, 0.f);
                wb2.h2[q] = pk2(0.f, 0.f);
            }
        }
        floatx16 g1acc = {};
        g1acc = __builtin_amdgcn_mfma_f32_32x32x16_f16(xa1.v, wb1.v, g1acc, 0, 0, 0);
        g1acc = __builtin_amdgcn_mfma_f32_32x32x16_f16(xa2.v, wb2.v, g1acc, 0, 0, 0);

#pragma unroll
        for (int i = 0; i < 16; ++i) {
            const int row = (i & 3) + 8*(i >> 2) + 4*hl;
            g1S[row*264 + jcol] = (__fp16)fmaxf(g1acc[i] + bg1v, 0.0f);
        }
    }
    __syncthreads();

    // GEMM2: g2 = relu(g1 @ Wg2 + bg2); dot Wg3; exp.
    // First K-batch from register prefetch; later batches double-buffered.
    {
        floatx16 acc2 = {};
        const __fp16* arow = g1S + j32 * 264;

        H8 wB[4], wBn[4];
#pragma unroll
        for (int q = 0; q < 4; ++q)
#pragma unroll
            for (int t = 0; t < 4; ++t)
                wB[q].h2[t] = pk2(wg2p[q*8 + 2*t], wg2p[q*8 + 2*t + 1]);

#pragma unroll
        for (int c = 0; c < 4; ++c) {
            if (c < 3) {
#pragma unroll
                for (int q = 0; q < 4; ++q) {
                    const int kb = (c*4 + 4 + q)*16 + hl*8;
#pragma unroll
                    for (int t = 0; t < 4; ++t)
                        wBn[q].h2[t] = pk2(Wg2[(kb + 2*t)*256 + jcol],
                                           Wg2[(kb + 2*t + 1)*256 + jcol]);
                }
            }
#pragma unroll
            for (int q = 0; q < 4; ++q) {
                H8 af;
                af.v = *(const half8*)(arow + (c*4 + q)*16 + hl*8);
                acc2 = __builtin_amdgcn_mfma_f32_32x32x16_f16(af.v, wB[q].v, acc2, 0, 0, 0);
            }
#pragma unroll
            for (int q = 0; q < 4; ++q) wB[q] = wBn[q];
        }

        float part[16];
#pragma unroll
        for (int i = 0; i < 16; ++i)
            part[i] = fmaxf(acc2[i] + bg2v, 0.0f) * w3vv;
#pragma unroll
        for (int off = 1; off <= 16; off <<= 1) {
#pragma unroll
            for (int i = 0; i < 16; ++i) part[i] += __shfl_xor(part[i], off);
        }
        float* redS = &sA[0][0];
        if ((lane & 31) == 0) {
#pragma unroll
            for (int i = 0; i < 16; ++i) {
                const int row = (i & 3) + 8*(i >> 2) + 4*hl;
                redS[wv*32 + row] = part[i];
            }
        }
        __syncthreads();

        if (tid < 32) {
            float v = bg3v;
#pragma unroll
            for (int w = 0; w < 8; ++w) v += redS[w*32 + tid];
            out[n0 + tid] = __expf(v);
        }
    }
}

extern "C" void kernel_launch(void* const* d_in, const int* in_sizes, int n_in,
                              void* d_out, int out_size, void* d_ws, size_t ws_size,
                              hipStream_t stream)
{
    const float* r   = (const float*)d_in[0];
    const float* rp  = (const float*)d_in[1];
    const float* cx  = (const float*)d_in[2];
    const float* cy  = (const float*)d_in[3];
    const float* Wa1 = (const float*)d_in[4];
    const float* Wa2 = (const float*)d_in[5];
    const float* Wa3 = (const float*)d_in[6];
    const float* Wp1 = (const float*)d_in[7];
    const float* bp1 = (const float*)d_in[8];
    const float* Wp2 = (const float*)d_in[9];
    const float* bp2 = (const float*)d_in[10];
    const float* Wg1 = (const float*)d_in[11];
    const float* bg1 = (const float*)d_in[12];
    const float* Wg2 = (const float*)d_in[13];
    const float* bg2 = (const float*)d_in[14];
    const float* Wg3 = (const float*)d_in[15];
    const float* bg3 = (const float*)d_in[16];

    hipLaunchKernelGGL(k_fused, dim3(N_/32), dim3(512), 0, stream,
                       r, rp, cx, cy, Wa1, Wa2, Wa3, Wp1, bp1, Wp2, bp2,
                       Wg1, bg1, Wg2, bg2, Wg3, bg3, (float*)d_out);
}

// Round 8
// 110.489 us; speedup vs baseline: 1.0001x; 1.0001x over previous
//
#include <hip/hip_runtime.h>
#include <math.h>

#define N_ 8192
#define P_ 512

typedef __fp16 half8  __attribute__((ext_vector_type(8)));
typedef __fp16 half2t __attribute__((ext_vector_type(2)));
typedef float  floatx16 __attribute__((ext_vector_type(16)));

union H8 { half8 v; half2t h2[4]; };

static __device__ __forceinline__ half2t pk2(float a, float b) {
    return __builtin_amdgcn_cvt_pkrtz(a, b);
}

// LDS region0 (bytes):
//   phase A: bpS 512 rows x 48 halfs (96 B/row) = 49152
//   phase C: g1S (32x264 halfs = 16896) @0 ; hpS (32x33 f32 = 4224) @17408 ;
//            xS (32x25 f32 = 3200) @21760
#define HP_OFF 17408
#define XS_OFF 21760

// 256 blocks x 512 thr. BEST-MEASURED KERNEL (108.55us, round 4) restored
// verbatim after rounds 5-7 all regressed:
//  r5: prefetch widened to 64 f32 -> VGPR collapse to 64 + 18MB scratch
//      spill traffic (126us). 32-f32 prefetch is the proven safe size.
//  r6: p-loop register double-buffer added addr VALU to the issue-bound
//      loop (+1.6us). The p-loop must stay at this minimal form.
//  r7: shfl_xor -> v_permlane32_swap moved work ONTO the saturated VALU
//      pipe (DS pipe had slack; its wait overlapped by co-resident wave)
//      (+1.9us).
// Mechanism of this kernel's win over the 110.2-111.7us base: the 268MB
// poison fill evicts L2+L3 every iteration; all phase-B/C weight reads are
// ~900-cyc cold HBM misses. The p-loop has no VMEM ops, so the post-p-loop
// batched prefetch issues ALL cold misses concurrently and the sA barrier
// drains them in ~one round trip, instead of serial per-use stalls behind
// barriers. No prefetch register lives across the p-loop.
__global__ __launch_bounds__(512, 4) void k_fused(
    const float* __restrict__ r,
    const float* __restrict__ rp,
    const float* __restrict__ coeff_x,
    const float* __restrict__ coeff_y,
    const float* __restrict__ Wa1,
    const float* __restrict__ Wa2,
    const float* __restrict__ Wa3,
    const float* __restrict__ Wp1,
    const float* __restrict__ bp1,
    const float* __restrict__ Wp2,
    const float* __restrict__ bp2,
    const float* __restrict__ Wg1,
    const float* __restrict__ bg1,
    const float* __restrict__ Wg2,
    const float* __restrict__ bg2,
    const float* __restrict__ Wg3,
    const float* __restrict__ bg3,
    float* __restrict__ out)
{
    __shared__ __align__(16) unsigned char reg0[49152];
    __shared__ __align__(16) float4 cyS[512];
    __shared__ float sA[8][32];          // also reused as redS
    __shared__ float aoA[4][8][32];
    __shared__ float aoS[32][4];

    const int tid  = threadIdx.x;
    const int n0   = blockIdx.x * 32;
    const int lane = tid & 63;
    const int wv   = tid >> 6;           // 8 waves
    const int j32  = lane & 31;
    const int hl   = lane >> 5;
    const int k0g  = hl * 8;

    // ================= Phase A: attention =================
    {
        const float2 cx = ((const float2*)coeff_x)[tid];
        half2t* wrow = (half2t*)(reg0 + tid * 96);
#pragma unroll
        for (int q = 0; q < 16; ++q) {
            const float b0 = cx.x * Wa1[64 + 2*q]     + cx.y * Wa1[96 + 2*q];
            const float b1 = cx.x * Wa1[64 + 2*q + 1] + cx.y * Wa1[96 + 2*q + 1];
            wrow[q] = pk2(b0, b1);
        }
        cyS[tid] = ((const float4*)coeff_y)[tid];
    }

    H8 anh1, anh2;
    {
        const float2 rv = ((const float2*)r)[2 * (n0 + j32)];
#pragma unroll
        for (int q = 0; q < 4; ++q) {
            const int k1 = k0g + 2*q, k2 = 16 + k0g + 2*q;
            anh1.h2[q] = pk2(rv.x*Wa1[k1]   + rv.y*Wa1[32+k1],
                             rv.x*Wa1[k1+1] + rv.y*Wa1[32+k1+1]);
            anh2.h2[q] = pk2(rv.x*Wa1[k2]   + rv.y*Wa1[32+k2],
                             rv.x*Wa1[k2+1] + rv.y*Wa1[32+k2+1]);
        }
    }
    H8 af1, af2;
#pragma unroll
    for (int q = 0; q < 4; ++q) {
        af1.h2[q] = pk2(Wa2[(k0g + 2*q)     * 32 + j32],
                        Wa2[(k0g + 2*q + 1) * 32 + j32]);
        af2.h2[q] = pk2(Wa2[(16 + k0g + 2*q)     * 32 + j32],
                        Wa2[(16 + k0g + 2*q + 1) * 32 + j32]);
    }
    half2t w3h[8];
#pragma unroll
    for (int q = 0; q < 8; ++q) {
        const int r0 = ((2*q) & 3) + 8*(q >> 1) + 4*hl;
        w3h[q] = pk2(Wa3[r0], Wa3[r0 + 1]);
    }

    __syncthreads();

    const half2t zero2 = pk2(0.f, 0.f);
    float s = 0.0f, aox = 0.f, aoy = 0.f, aoz = 0.f, aow = 0.f;

#pragma unroll 2
    for (int pl = 0; pl < 64; ++pl) {
        const int ploc = wv * 64 + pl;
        const half2t* rowq = (const half2t*)(reg0 + ploc * 96) + hl * 4;

        H8 bf1, bf2;
#pragma unroll
        for (int q = 0; q < 4; ++q) {
            bf1.h2[q] = __builtin_elementwise_max(anh1.h2[q] + rowq[q],     zero2);
            bf2.h2[q] = __builtin_elementwise_max(anh2.h2[q] + rowq[8 + q], zero2);
        }

        floatx16 zc = {};
        floatx16 acc = __builtin_amdgcn_mfma_f32_32x32x16_f16(af1.v, bf1.v, zc, 0, 0, 0);
        acc = __builtin_amdgcn_mfma_f32_32x32x16_f16(af2.v, bf2.v, acc, 0, 0, 0);

        float d0, d1, d2, d3;
        {
            half2t z0 = __builtin_elementwise_max(pk2(acc[0],  acc[1]),  zero2);
            half2t z1 = __builtin_elementwise_max(pk2(acc[2],  acc[3]),  zero2);
            half2t z2 = __builtin_elementwise_max(pk2(acc[4],  acc[5]),  zero2);
            half2t z3 = __builtin_elementwise_max(pk2(acc[6],  acc[7]),  zero2);
            half2t z4 = __builtin_elementwise_max(pk2(acc[8],  acc[9]),  zero2);
            half2t z5 = __builtin_elementwise_max(pk2(acc[10], acc[11]), zero2);
            half2t z6 = __builtin_elementwise_max(pk2(acc[12], acc[13]), zero2);
            half2t z7 = __builtin_elementwise_max(pk2(acc[14], acc[15]), zero2);
            d0 = __builtin_amdgcn_fdot2(z1, w3h[1], __builtin_amdgcn_fdot2(z0, w3h[0], 0.f, false), false);
            d1 = __builtin_amdgcn_fdot2(z3, w3h[3], __builtin_amdgcn_fdot2(z2, w3h[2], 0.f, false), false);
            d2 = __builtin_amdgcn_fdot2(z5, w3h[5], __builtin_amdgcn_fdot2(z4, w3h[4], 0.f, false), false);
            d3 = __builtin_amdgcn_fdot2(z7, w3h[7], __builtin_amdgcn_fdot2(z6, w3h[6], 0.f, false), false);
        }
        float dot = (d0 + d1) + (d2 + d3);
        dot += __shfl_xor(dot, 32);

        const float e = __expf(dot);   // logits ~N(0,1.3): no-max-sub safe
        const float4 cyv = cyS[ploc];
        s   += e;
        aox += e * cyv.x;
        aoy += e * cyv.y;
        aoz += e * cyv.z;
        aow += e * cyv.w;
    }

    // -------- post-p-loop cold-HBM register prefetch (phase B/C weights).
    // Issued here so latency hides under sA-write + 2 barriers + softmax
    // reduce + phase B; no live range crosses the p-loop. --------
    const int jcol = (wv << 5) + j32;
    const int nB = tid & 31;
    const int iB = tid >> 5;             // 0..15

    float wg2p[32];                      // GEMM2 first K-batch (q=0..3)
#pragma unroll
    for (int q = 0; q < 4; ++q)
#pragma unroll
        for (int t = 0; t < 4; ++t) {
            const int kb = q*16 + hl*8 + 2*t;
            wg2p[q*8 + 2*t]     = Wg2[kb*256 + jcol];
            wg2p[q*8 + 2*t + 1] = Wg2[(kb+1)*256 + jcol];
        }
    float wg1f[8], wg1g[8];
    const float bg1v = bg1[jcol];
#pragma unroll
    for (int q = 0; q < 4; ++q) {
        wg1f[2*q]   = Wg1[(k0g + 2*q)*256 + jcol];
        wg1f[2*q+1] = Wg1[(k0g + 2*q + 1)*256 + jcol];
        wg1g[2*q]   = Wg1[(16 + 2*q)*256 + jcol];
        wg1g[2*q+1] = Wg1[(17 + 2*q)*256 + jcol];
    }
    float xpre = 0.f;
    if (tid < 256) {
        const int nn = tid >> 3, k = tid & 7;
        xpre = (k < 4) ? r[(n0+nn)*4 + k] : rp[(n0+nn)*4 + k - 4];
    }
    float wpb[2], wpA[2][4];
#pragma unroll
    for (int rep = 0; rep < 2; ++rep) {
        const int i = iB + rep*16;
        wpb[rep]    = bp1[i];
        wpA[rep][0] = Wp1[i];
        wpA[rep][1] = Wp1[32 + i];
        wpA[rep][2] = Wp1[64 + i];
        wpA[rep][3] = Wp1[96 + i];
    }
    const float bp2v = bp2[iB];
    const float bg2v = bg2[jcol];
    const float w3vv = Wg3[jcol];
    const float bg3v = bg3[0];

    if (lane < 32) {
        sA[wv][lane]      = s;
        aoA[0][wv][lane]  = aox;
        aoA[1][wv][lane]  = aoy;
        aoA[2][wv][lane]  = aoz;
        aoA[3][wv][lane]  = aow;
    }
    __syncthreads();

    if (tid < 32) {
        float S = 0.f, A0 = 0.f, A1 = 0.f, A2 = 0.f, A3 = 0.f;
#pragma unroll
        for (int w = 0; w < 8; ++w) {
            S  += sA[w][tid];
            A0 += aoA[0][w][tid];
            A1 += aoA[1][w][tid];
            A2 += aoA[2][w][tid];
            A3 += aoA[3][w][tid];
        }
        const float inv = 1.0f / S;
        aoS[tid][0] = A0 * inv;
        aoS[tid][1] = A1 * inv;
        aoS[tid][2] = A2 * inv;
        aoS[tid][3] = A3 * inv;
    }
    __syncthreads();

    // ================= Phase B: c-MLP + x assembly =================
    float* hpS = (float*)(reg0 + HP_OFF);
    float* xS  = (float*)(reg0 + XS_OFF);

    if (tid < 256) {
        const int nn = tid >> 3, k = tid & 7;
        xS[nn*25 + k] = xpre;
    }
    {
        const float a0 = aoS[nB][0], a1 = aoS[nB][1], a2 = aoS[nB][2], a3 = aoS[nB][3];
#pragma unroll
        for (int rep = 0; rep < 2; ++rep) {
            const int i = iB + rep*16;
            float a = wpb[rep] + a0*wpA[rep][0] + a1*wpA[rep][1]
                               + a2*wpA[rep][2] + a3*wpA[rep][3];
            hpS[nB*33 + i] = fmaxf(a, 0.0f);
        }
    }
    __syncthreads();

    {
        float a = bp2v;
#pragma unroll
        for (int i = 0; i < 32; ++i) a += hpS[nB*33 + i] * Wp2[i*16 + iB];
        xS[nB*25 + 8 + iB] = a;
    }
    __syncthreads();

    // ================= Phase C: g-network via MFMA =================
    __fp16* g1S = (__fp16*)reg0;

    // GEMM1: g1 = relu(x @ Wg1 + bg1), K=24 padded to 32
    {
        H8 xa1, xa2, wb1, wb2;
        const float* xrow = xS + j32 * 25;
#pragma unroll
        for (int q = 0; q < 4; ++q) {
            xa1.h2[q] = pk2(xrow[k0g + 2*q], xrow[k0g + 2*q + 1]);
            wb1.h2[q] = pk2(wg1f[2*q], wg1f[2*q+1]);
            if (hl == 0) {
                xa2.h2[q] = pk2(xrow[16 + 2*q], xrow[16 + 2*q + 1]);
                wb2.h2[q] = pk2(wg1g[2*q], wg1g[2*q+1]);
            } else {
                xa2.h2[q] = pk2(0.f, 0.f);
                wb2.h2[q] = pk2(0.f, 0.f);
            }
        }
        floatx16 g1acc = {};
        g1acc = __builtin_amdgcn_mfma_f32_32x32x16_f16(xa1.v, wb1.v, g1acc, 0, 0, 0);
        g1acc = __builtin_amdgcn_mfma_f32_32x32x16_f16(xa2.v, wb2.v, g1acc, 0, 0, 0);

#pragma unroll
        for (int i = 0; i < 16; ++i) {
            const int row = (i & 3) + 8*(i >> 2) + 4*hl;
            g1S[row*264 + jcol] = (__fp16)fmaxf(g1acc[i] + bg1v, 0.0f);
        }
    }
    __syncthreads();

    // GEMM2: g2 = relu(g1 @ Wg2 + bg2); dot Wg3; exp.
    // First K-batch from register prefetch; later batches double-buffered.
    {
        floatx16 acc2 = {};
        const __fp16* arow = g1S + j32 * 264;

        H8 wB[4], wBn[4];
#pragma unroll
        for (int q = 0; q < 4; ++q)
#pragma unroll
            for (int t = 0; t < 4; ++t)
                wB[q].h2[t] = pk2(wg2p[q*8 + 2*t], wg2p[q*8 + 2*t + 1]);

#pragma unroll
        for (int c = 0; c < 4; ++c) {
            if (c < 3) {
#pragma unroll
                for (int q = 0; q < 4; ++q) {
                    const int kb = (c*4 + 4 + q)*16 + hl*8;
#pragma unroll
                    for (int t = 0; t < 4; ++t)
                        wBn[q].h2[t] = pk2(Wg2[(kb + 2*t)*256 + jcol],
                                           Wg2[(kb + 2*t + 1)*256 + jcol]);
                }
            }
#pragma unroll
            for (int q = 0; q < 4; ++q) {
                H8 af;
                af.v = *(const half8*)(arow + (c*4 + q)*16 + hl*8);
                acc2 = __builtin_amdgcn_mfma_f32_32x32x16_f16(af.v, wB[q].v, acc2, 0, 0, 0);
            }
#pragma unroll
            for (int q = 0; q < 4; ++q) wB[q] = wBn[q];
        }

        float part[16];
#pragma unroll
        for (int i = 0; i < 16; ++i)
            part[i] = fmaxf(acc2[i] + bg2v, 0.0f) * w3vv;
#pragma unroll
        for (int off = 1; off <= 16; off <<= 1) {
#pragma unroll
            for (int i = 0; i < 16; ++i) part[i] += __shfl_xor(part[i], off);
        }
        float* redS = &sA[0][0];
        if ((lane & 31) == 0) {
#pragma unroll
            for (int i = 0; i < 16; ++i) {
                const int row = (i & 3) + 8*(i >> 2) + 4*hl;
                redS[wv*32 + row] = part[i];
            }
        }
        __syncthreads();

        if (tid < 32) {
            float v = bg3v;
#pragma unroll
            for (int w = 0; w < 8; ++w) v += redS[w*32 + tid];
            out[n0 + tid] = __expf(v);
        }
    }
}

extern "C" void kernel_launch(void* const* d_in, const int* in_sizes, int n_in,
                              void* d_out, int out_size, void* d_ws, size_t ws_size,
                              hipStream_t stream)
{
    const float* r   = (const float*)d_in[0];
    const float* rp  = (const float*)d_in[1];
    const float* cx  = (const float*)d_in[2];
    const float* cy  = (const float*)d_in[3];
    const float* Wa1 = (const float*)d_in[4];
    const float* Wa2 = (const float*)d_in[5];
    const float* Wa3 = (const float*)d_in[6];
    const float* Wp1 = (const float*)d_in[7];
    const float* bp1 = (const float*)d_in[8];
    const float* Wp2 = (const float*)d_in[9];
    const float* bp2 = (const float*)d_in[10];
    const float* Wg1 = (const float*)d_in[11];
    const float* bg1 = (const float*)d_in[12];
    const float* Wg2 = (const float*)d_in[13];
    const float* bg2 = (const float*)d_in[14];
    const float* Wg3 = (const float*)d_in[15];
    const float* bg3 = (const float*)d_in[16];

    hipLaunchKernelGGL(k_fused, dim3(N_/32), dim3(512), 0, stream,
                       r, rp, cx, cy, Wa1, Wa2, Wa3, Wp1, bp1, Wp2, bp2,
                       Wg1, bg1, Wg2, bg2, Wg3, bg3, (float*)d_out);
}